// Round 1
// baseline (611.375 us; speedup 1.0000x reference)
//
#include <hip/hip_runtime.h>
#include <hip/hip_bf16.h>
#include <cstdint>

typedef __attribute__((ext_vector_type(8))) __bf16 bf16x8;
typedef __attribute__((ext_vector_type(4))) float f32x4;
typedef unsigned short u16;

#define DEV static __device__ __forceinline__

constexpr float ATT_SCALE = 0.125f;   // 64^-0.5 (module uses dimHead=64)
constexpr float LN_EPS = 1e-3f;

DEV void gload16(const void* g, void* l) {
  __builtin_amdgcn_global_load_lds((__attribute__((address_space(1))) void*)(g),
                                   (__attribute__((address_space(3))) void*)(l),
                                   16, 0, 0);
}

DEV u16 f2b(float f) { __hip_bfloat16 h = __float2bfloat16(f); return __builtin_bit_cast(u16, h); }

// ---------------- weight transpose + convert ----------------
// in: [R][C] f32 row-major; out: [C][R] bf16, out row jp = perm(d).
// PERM=1: d -> (i = d%3, h = (d/3)%8, c = d/24), jp = i*1024 + h*128 + c.
template<int PERM>
__global__ __launch_bounds__(256)
void k_transpose(const float* __restrict__ in, __hip_bfloat16* __restrict__ out,
                 int R, int C) {
  __shared__ float t[64][65];
  int d0 = blockIdx.x * 64, k0 = blockIdx.y * 64;
  int tid = threadIdx.x;
  int c64 = tid & 63, r4 = tid >> 6;
#pragma unroll
  for (int i = 0; i < 16; i++) {
    int kr = i * 4 + r4;
    t[c64][kr] = in[(size_t)(k0 + kr) * C + d0 + c64];
  }
  __syncthreads();
#pragma unroll
  for (int i = 0; i < 16; i++) {
    int dr = i * 4 + r4;
    int d = d0 + dr;
    int jp = PERM ? ((d % 3) * 1024 + ((d / 3) & 7) * 128 + (d / 24)) : d;
    out[(size_t)jp * R + k0 + c64] = __float2bfloat16(t[dr][c64]);
  }
}

// ---------------- LayerNorm (f32 in -> bf16 out) ----------------
__global__ __launch_bounds__(256)
void k_ln(const float* __restrict__ in, const float* __restrict__ g,
          const float* __restrict__ b, __hip_bfloat16* __restrict__ out) {
  int row = blockIdx.x, tid = threadIdx.x;
  const float4* in4 = (const float4*)(in + (size_t)row * 1024);
  float4 v = in4[tid];
  float s = v.x + v.y + v.z + v.w;
  float ss = v.x * v.x + v.y * v.y + v.z * v.z + v.w * v.w;
#pragma unroll
  for (int off = 32; off; off >>= 1) { s += __shfl_down(s, off); ss += __shfl_down(ss, off); }
  __shared__ float red[8];
  int w = tid >> 6, lane = tid & 63;
  if (lane == 0) { red[w] = s; red[4 + w] = ss; }
  __syncthreads();
  if (tid == 0) {
    float S = red[0] + red[1] + red[2] + red[3];
    float SS = red[4] + red[5] + red[6] + red[7];
    float mu = S * (1.f / 1024.f);
    float var = SS * (1.f / 1024.f) - mu * mu;
    red[0] = mu; red[1] = rsqrtf(var + LN_EPS);
  }
  __syncthreads();
  float mu = red[0], rs = red[1];
  int c = tid * 4;
  ushort4 o;
  o.x = f2b((v.x - mu) * rs * g[c + 0] + b[c + 0]);
  o.y = f2b((v.y - mu) * rs * g[c + 1] + b[c + 1]);
  o.z = f2b((v.z - mu) * rs * g[c + 2] + b[c + 2]);
  o.w = f2b((v.w - mu) * rs * g[c + 3] + b[c + 3]);
  ((ushort4*)((u16*)out + (size_t)row * 1024))[tid] = o;
}

// ---------------- GEMM: C[M,N] = A[M,K] * Bt[N,K]^T, m97-style ----------------
// MODE 0: qkv  -> relu(+b3 permuted), scatter q/k [B,H,N,C], vT [B,H,C,N]
// MODE 1: mlp1 -> relu(+b1) -> bf16 outQ [M,Nout]
// MODE 2: mlp2 -> +b2 + resid -> f32 outF [M,Nout]
template<int MODE>
__global__ __launch_bounds__(256, 2)
void k_gemm(const __hip_bfloat16* __restrict__ A,
            const __hip_bfloat16* __restrict__ Bt,
            const float* __restrict__ bias,
            const float* __restrict__ resid,
            float* __restrict__ outF,
            __hip_bfloat16* __restrict__ outQ,
            __hip_bfloat16* __restrict__ outK,
            __hip_bfloat16* __restrict__ outV,
            int K, int Nout) {
  __shared__ alignas(16) __hip_bfloat16 Asm[128 * 32];
  __shared__ alignas(16) __hip_bfloat16 Bsm[128 * 32];
  int tid = threadIdx.x, w = tid >> 6, lane = tid & 63;
  int wr = w >> 1, wc = w & 1;
  int lr = lane >> 4, lc = lane & 15;
  int m0 = blockIdx.y * 128, n0 = blockIdx.x * 128;
  f32x4 acc[4][4] = {};
  const __hip_bfloat16* aG = A + (size_t)(m0 + (tid >> 2)) * K + (tid & 3) * 8;
  const __hip_bfloat16* bG = Bt + (size_t)(n0 + (tid >> 2)) * K + (tid & 3) * 8;
  char* aB = (char*)Asm + w * 1024;
  char* bB = (char*)Bsm + w * 1024;
  for (int k0 = 0; k0 < K; k0 += 32) {
    gload16(aG + k0, aB);
    gload16(aG + (size_t)64 * K + k0, aB + 4096);
    gload16(bG + k0, bB);
    gload16(bG + (size_t)64 * K + k0, bB + 4096);
    __syncthreads();
    bf16x8 af[4], bfr[4];
#pragma unroll
    for (int mi = 0; mi < 4; mi++)
      af[mi] = *(const bf16x8*)(Asm + (wr * 64 + mi * 16 + lc) * 32 + lr * 8);
#pragma unroll
    for (int ni = 0; ni < 4; ni++)
      bfr[ni] = *(const bf16x8*)(Bsm + (wc * 64 + ni * 16 + lc) * 32 + lr * 8);
#pragma unroll
    for (int mi = 0; mi < 4; mi++)
#pragma unroll
      for (int ni = 0; ni < 4; ni++)
        acc[mi][ni] = __builtin_amdgcn_mfma_f32_16x16x32_bf16(af[mi], bfr[ni], acc[mi][ni], 0, 0, 0);
    __syncthreads();
  }
#pragma unroll
  for (int mi = 0; mi < 4; mi++) {
#pragma unroll
    for (int ni = 0; ni < 4; ni++) {
      int jp = n0 + wc * 64 + ni * 16 + lc;
#pragma unroll
      for (int r = 0; r < 4; r++) {
        int m = m0 + wr * 64 + mi * 16 + lr * 4 + r;
        float v = acc[mi][ni][r];
        if (MODE == 0) {
          int i = jp >> 10, h = (jp >> 7) & 7, c = jp & 127;
          v += bias[c * 24 + h * 3 + i];
          v = fmaxf(v, 0.f);
          __hip_bfloat16 bv = __float2bfloat16(v);
          int b_ = m >> 11, n = m & 2047;
          size_t bh = (size_t)(b_ * 8 + h);
          if (i == 0)      outQ[(bh * 2048 + n) * 128 + c] = bv;
          else if (i == 1) outK[(bh * 2048 + n) * 128 + c] = bv;
          else             outV[(bh * 128 + c) * 2048 + n] = bv;
        } else if (MODE == 1) {
          v += bias[jp];
          v = fmaxf(v, 0.f);
          outQ[(size_t)m * Nout + jp] = __float2bfloat16(v);
        } else {
          v += bias[jp] + resid[(size_t)m * Nout + jp];
          outF[(size_t)m * Nout + jp] = v;
        }
      }
    }
  }
}

// ---------------- flash attention + residual ----------------
// q,k: [BH=32][N=2048][C=128] bf16 ; vT: [BH][C][N] bf16 ; x,y: [B,N,1024] f32
__global__ __launch_bounds__(256, 1)
void k_attn(const __hip_bfloat16* __restrict__ qb,
            const __hip_bfloat16* __restrict__ kb,
            const __hip_bfloat16* __restrict__ vtb,
            const float* __restrict__ x,
            float* __restrict__ y) {
  __shared__ alignas(16) __hip_bfloat16 Kl[64 * 128];
  __shared__ alignas(16) __hip_bfloat16 Vl[128 * 64];
  __shared__ alignas(16) __hip_bfloat16 Pl[4 * 32 * 72];
  int tid = threadIdx.x, w = tid >> 6, lane = tid & 63;
  int lr = lane >> 4, lc = lane & 15;
  int qt = blockIdx.x, bh = blockIdx.y;
  int b_ = bh >> 3, h = bh & 7;
  int q0 = qt * 128;
  size_t bhN = (size_t)bh * 2048;

  bf16x8 qf[2][4];
#pragma unroll
  for (int mi = 0; mi < 2; mi++)
#pragma unroll
    for (int ks = 0; ks < 4; ks++)
      qf[mi][ks] = *(const bf16x8*)(qb + (bhN + q0 + w * 32 + mi * 16 + lc) * 128 + ks * 32 + lr * 8);

  f32x4 oacc[2][8] = {};
  float mrun[2][4], lrun[2][4];
#pragma unroll
  for (int mi = 0; mi < 2; mi++)
#pragma unroll
    for (int r = 0; r < 4; r++) { mrun[mi][r] = -1e30f; lrun[mi][r] = 0.f; }

  const __hip_bfloat16* kG = kb + (bhN + (tid >> 4)) * 128 + (tid & 15) * 8;
  const __hip_bfloat16* vG = vtb + ((size_t)bh * 128 + (tid >> 3)) * 2048 + (tid & 7) * 8;
  char* kB = (char*)Kl + w * 1024;
  char* vB = (char*)Vl + w * 1024;

  for (int kv0 = 0; kv0 < 2048; kv0 += 64) {
#pragma unroll
    for (int p = 0; p < 4; p++)
      gload16(kG + (size_t)(kv0 + p * 16) * 128, kB + p * 4096);
#pragma unroll
    for (int p = 0; p < 4; p++)
      gload16(vG + kv0 + (size_t)p * 32 * 2048, vB + p * 4096);
    __syncthreads();

    // S = Q K^T (per wave: 32 q rows x 64 kv cols)
    f32x4 sf[2][4] = {};
#pragma unroll
    for (int ks = 0; ks < 4; ks++) {
      bf16x8 kfr[4];
#pragma unroll
      for (int ni = 0; ni < 4; ni++)
        kfr[ni] = *(const bf16x8*)(Kl + (ni * 16 + lc) * 128 + ks * 32 + lr * 8);
#pragma unroll
      for (int mi = 0; mi < 2; mi++)
#pragma unroll
        for (int ni = 0; ni < 4; ni++)
          sf[mi][ni] = __builtin_amdgcn_mfma_f32_16x16x32_bf16(qf[mi][ks], kfr[ni], sf[mi][ni], 0, 0, 0);
    }

    // online softmax
#pragma unroll
    for (int mi = 0; mi < 2; mi++) {
#pragma unroll
      for (int r = 0; r < 4; r++) {
        float tmax = fmaxf(fmaxf(sf[mi][0][r], sf[mi][1][r]), fmaxf(sf[mi][2][r], sf[mi][3][r]));
#pragma unroll
        for (int off = 1; off < 16; off <<= 1) tmax = fmaxf(tmax, __shfl_xor(tmax, off, 16));
        tmax *= ATT_SCALE;
        float mnew = fmaxf(mrun[mi][r], tmax);
        float alpha = __expf(mrun[mi][r] - mnew);
        mrun[mi][r] = mnew;
        float rs = 0.f;
#pragma unroll
        for (int ni = 0; ni < 4; ni++) {
          float p = __expf(sf[mi][ni][r] * ATT_SCALE - mnew);
          sf[mi][ni][r] = p;
          rs += p;
        }
#pragma unroll
        for (int off = 1; off < 16; off <<= 1) rs += __shfl_xor(rs, off, 16);
        lrun[mi][r] = lrun[mi][r] * alpha + rs;
#pragma unroll
        for (int nc = 0; nc < 8; nc++) oacc[mi][nc][r] *= alpha;
      }
    }

    // P -> LDS (per-wave region, padded rows: 72 elems)
#pragma unroll
    for (int mi = 0; mi < 2; mi++)
#pragma unroll
      for (int ni = 0; ni < 4; ni++)
#pragma unroll
        for (int r = 0; r < 4; r++)
          Pl[w * 2304 + (mi * 16 + lr * 4 + r) * 72 + ni * 16 + lc] = __float2bfloat16(sf[mi][ni][r]);
    asm volatile("s_waitcnt lgkmcnt(0)" ::: "memory");

    // O += P V
#pragma unroll
    for (int ks2 = 0; ks2 < 2; ks2++) {
      bf16x8 pa[2];
#pragma unroll
      for (int mi = 0; mi < 2; mi++)
        pa[mi] = *(const bf16x8*)(Pl + w * 2304 + (mi * 16 + lc) * 72 + ks2 * 32 + lr * 8);
#pragma unroll
      for (int nc = 0; nc < 8; nc++) {
        bf16x8 vf = *(const bf16x8*)(Vl + (nc * 16 + lc) * 64 + ks2 * 32 + lr * 8);
#pragma unroll
        for (int mi = 0; mi < 2; mi++)
          oacc[mi][nc] = __builtin_amdgcn_mfma_f32_16x16x32_bf16(pa[mi], vf, oacc[mi][nc], 0, 0, 0);
      }
    }
    __syncthreads();
  }

  // epilogue: y = O/l + x
#pragma unroll
  for (int mi = 0; mi < 2; mi++)
#pragma unroll
    for (int r = 0; r < 4; r++) {
      int n = q0 + w * 32 + mi * 16 + lr * 4 + r;
      float inv = 1.f / lrun[mi][r];
      size_t base = ((size_t)(b_ * 2048 + n)) * 1024 + h * 128;
#pragma unroll
      for (int nc = 0; nc < 8; nc++) {
        int c = nc * 16 + lc;
        y[base + c] = oacc[mi][nc][r] * inv + x[base + c];
      }
    }
}

// ---------------- launch ----------------
extern "C" void kernel_launch(void* const* d_in, const int* in_sizes, int n_in,
                              void* d_out, int out_size, void* d_ws, size_t ws_size,
                              hipStream_t stream) {
  const float* x   = (const float*)d_in[0];
  const float* lng = (const float*)d_in[1];
  const float* lnb = (const float*)d_in[2];
  const float* w3  = (const float*)d_in[3];
  const float* b3  = (const float*)d_in[4];
  const float* w1  = (const float*)d_in[5];
  const float* b1  = (const float*)d_in[6];
  const float* w2  = (const float*)d_in[7];
  const float* b2  = (const float*)d_in[8];
  float* out = (float*)d_out;

  constexpr size_t M = 8192;
  __hip_bfloat16* w3t  = (__hip_bfloat16*)d_ws;                 // [3072][1024]
  __hip_bfloat16* w1t  = w3t + (size_t)3072 * 1024;             // [4096][1024]
  __hip_bfloat16* w2t  = w1t + (size_t)4096 * 1024;             // [1024][4096]
  __hip_bfloat16* xln  = w2t + (size_t)4096 * 1024;             // [8192][1024] (also y1)
  __hip_bfloat16* qb   = xln + M * 1024;                        // [32][2048][128]
  __hip_bfloat16* kbuf = qb + M * 1024;
  __hip_bfloat16* vtb  = kbuf + M * 1024;
  __hip_bfloat16* hmid = qb;                                    // overlay: [8192][4096]

  // weights -> bf16 transposed (w3 with column permutation folded in)
  k_transpose<1><<<dim3(48, 16), 256, 0, stream>>>(w3, w3t, 1024, 3072);
  k_transpose<0><<<dim3(64, 16), 256, 0, stream>>>(w1, w1t, 1024, 4096);
  k_transpose<0><<<dim3(16, 64), 256, 0, stream>>>(w2, w2t, 4096, 1024);
  // LN1
  k_ln<<<dim3(M), 256, 0, stream>>>(x, lng, lnb, xln);
  // QKV GEMM + relu + scatter
  k_gemm<0><<<dim3(24, 64), 256, 0, stream>>>(xln, w3t, b3, nullptr, nullptr,
                                              qb, kbuf, vtb, 1024, 3072);
  // attention + residual -> y (in d_out)
  k_attn<<<dim3(16, 32), 256, 0, stream>>>(qb, kbuf, vtb, x, out);
  // LN2
  k_ln<<<dim3(M), 256, 0, stream>>>(out, lng, lnb, xln);
  // MLP
  k_gemm<1><<<dim3(32, 64), 256, 0, stream>>>(xln, w1t, b1, nullptr, nullptr,
                                              hmid, nullptr, nullptr, 1024, 4096);
  k_gemm<2><<<dim3(8, 64), 256, 0, stream>>>(hmid, w2t, b2, out, out,
                                             nullptr, nullptr, nullptr, 4096, 1024);
}

// Round 3
// 569.429 us; speedup vs baseline: 1.0737x; 1.0737x over previous
//
#include <hip/hip_runtime.h>
#include <hip/hip_bf16.h>
#include <cstdint>

typedef __attribute__((ext_vector_type(8))) __bf16 bf16x8;
typedef __attribute__((ext_vector_type(4))) float f32x4;
typedef unsigned short u16;

#define DEV static __device__ __forceinline__

constexpr float ATT_SCALE = 0.125f;   // 64^-0.5 (module uses dimHead=64)
constexpr float LN_EPS = 1e-3f;

DEV void gload16(const void* g, void* l) {
  __builtin_amdgcn_global_load_lds((__attribute__((address_space(1))) void*)(g),
                                   (__attribute__((address_space(3))) void*)(l),
                                   16, 0, 0);
}

DEV u16 f2b(float f) { __hip_bfloat16 h = __float2bfloat16(f); return __builtin_bit_cast(u16, h); }

// ---------------- weight transpose + convert ----------------
template<int PERM>
__global__ __launch_bounds__(256)
void k_transpose(const float* __restrict__ in, __hip_bfloat16* __restrict__ out,
                 int R, int C) {
  __shared__ float t[64][65];
  int d0 = blockIdx.x * 64, k0 = blockIdx.y * 64;
  int tid = threadIdx.x;
  int c64 = tid & 63, r4 = tid >> 6;
#pragma unroll
  for (int i = 0; i < 16; i++) {
    int kr = i * 4 + r4;
    t[c64][kr] = in[(size_t)(k0 + kr) * C + d0 + c64];
  }
  __syncthreads();
#pragma unroll
  for (int i = 0; i < 16; i++) {
    int dr = i * 4 + r4;
    int d = d0 + dr;
    int jp = PERM ? ((d % 3) * 1024 + ((d / 3) & 7) * 128 + (d / 24)) : d;
    out[(size_t)jp * R + k0 + c64] = __float2bfloat16(t[dr][c64]);
  }
}

// ---------------- LayerNorm (f32 in -> bf16 out) ----------------
__global__ __launch_bounds__(256)
void k_ln(const float* __restrict__ in, const float* __restrict__ g,
          const float* __restrict__ b, __hip_bfloat16* __restrict__ out) {
  int row = blockIdx.x, tid = threadIdx.x;
  const float4* in4 = (const float4*)(in + (size_t)row * 1024);
  float4 v = in4[tid];
  float s = v.x + v.y + v.z + v.w;
  float ss = v.x * v.x + v.y * v.y + v.z * v.z + v.w * v.w;
#pragma unroll
  for (int off = 32; off; off >>= 1) { s += __shfl_down(s, off); ss += __shfl_down(ss, off); }
  __shared__ float red[8];
  int w = tid >> 6, lane = tid & 63;
  if (lane == 0) { red[w] = s; red[4 + w] = ss; }
  __syncthreads();
  if (tid == 0) {
    float S = red[0] + red[1] + red[2] + red[3];
    float SS = red[4] + red[5] + red[6] + red[7];
    float mu = S * (1.f / 1024.f);
    float var = SS * (1.f / 1024.f) - mu * mu;
    red[0] = mu; red[1] = rsqrtf(var + LN_EPS);
  }
  __syncthreads();
  float mu = red[0], rs = red[1];
  int c = tid * 4;
  ushort4 o;
  o.x = f2b((v.x - mu) * rs * g[c + 0] + b[c + 0]);
  o.y = f2b((v.y - mu) * rs * g[c + 1] + b[c + 1]);
  o.z = f2b((v.z - mu) * rs * g[c + 2] + b[c + 2]);
  o.w = f2b((v.w - mu) * rs * g[c + 3] + b[c + 3]);
  ((ushort4*)((u16*)out + (size_t)row * 1024))[tid] = o;
}

// ---------------- GEMM: C[M,N] = A[M,K] * Bt[N,K]^T, m97-style ----------------
template<int MODE>
__global__ __launch_bounds__(256, 2)
void k_gemm(const __hip_bfloat16* __restrict__ A,
            const __hip_bfloat16* __restrict__ Bt,
            const float* __restrict__ bias,
            const float* __restrict__ resid,
            float* __restrict__ outF,
            __hip_bfloat16* __restrict__ outQ,
            __hip_bfloat16* __restrict__ outK,
            __hip_bfloat16* __restrict__ outV,
            int K, int Nout) {
  __shared__ alignas(16) __hip_bfloat16 Asm[128 * 32];
  __shared__ alignas(16) __hip_bfloat16 Bsm[128 * 32];
  int tid = threadIdx.x, w = tid >> 6, lane = tid & 63;
  int wr = w >> 1, wc = w & 1;
  int lr = lane >> 4, lc = lane & 15;
  int m0 = blockIdx.y * 128, n0 = blockIdx.x * 128;
  f32x4 acc[4][4] = {};
  const __hip_bfloat16* aG = A + (size_t)(m0 + (tid >> 2)) * K + (tid & 3) * 8;
  const __hip_bfloat16* bG = Bt + (size_t)(n0 + (tid >> 2)) * K + (tid & 3) * 8;
  char* aB = (char*)Asm + w * 1024;
  char* bB = (char*)Bsm + w * 1024;
  for (int k0 = 0; k0 < K; k0 += 32) {
    gload16(aG + k0, aB);
    gload16(aG + (size_t)64 * K + k0, aB + 4096);
    gload16(bG + k0, bB);
    gload16(bG + (size_t)64 * K + k0, bB + 4096);
    __syncthreads();
    bf16x8 af[4], bfr[4];
#pragma unroll
    for (int mi = 0; mi < 4; mi++)
      af[mi] = *(const bf16x8*)(Asm + (wr * 64 + mi * 16 + lc) * 32 + lr * 8);
#pragma unroll
    for (int ni = 0; ni < 4; ni++)
      bfr[ni] = *(const bf16x8*)(Bsm + (wc * 64 + ni * 16 + lc) * 32 + lr * 8);
#pragma unroll
    for (int mi = 0; mi < 4; mi++)
#pragma unroll
      for (int ni = 0; ni < 4; ni++)
        acc[mi][ni] = __builtin_amdgcn_mfma_f32_16x16x32_bf16(af[mi], bfr[ni], acc[mi][ni], 0, 0, 0);
    __syncthreads();
  }
#pragma unroll
  for (int mi = 0; mi < 4; mi++) {
#pragma unroll
    for (int ni = 0; ni < 4; ni++) {
      int jp = n0 + wc * 64 + ni * 16 + lc;
#pragma unroll
      for (int r = 0; r < 4; r++) {
        int m = m0 + wr * 64 + mi * 16 + lr * 4 + r;
        float v = acc[mi][ni][r];
        if (MODE == 0) {
          int i = jp >> 10, h = (jp >> 7) & 7, c = jp & 127;
          v += bias[c * 24 + h * 3 + i];
          v = fmaxf(v, 0.f);
          __hip_bfloat16 bv = __float2bfloat16(v);
          int b_ = m >> 11, n = m & 2047;
          size_t bh = (size_t)(b_ * 8 + h);
          if (i == 0)      outQ[(bh * 2048 + n) * 128 + c] = bv;
          else if (i == 1) outK[(bh * 2048 + n) * 128 + c] = bv;
          else             outV[(bh * 128 + c) * 2048 + n] = bv;
        } else if (MODE == 1) {
          v += bias[jp];
          v = fmaxf(v, 0.f);
          outQ[(size_t)m * Nout + jp] = __float2bfloat16(v);
        } else {
          v += bias[jp] + resid[(size_t)m * Nout + jp];
          outF[(size_t)m * Nout + jp] = v;
        }
      }
    }
  }
}

// ---------------- flash attention + residual ----------------
// q,k: [BH=32][N=2048][C=128] bf16 ; vT: [BH][C][N] bf16 ; x,y: [B,N,1024] f32
// QBLK=64 (1024 blocks), K/V LDS XOR-swizzled (linear gload_lds dest +
// pre-swizzled global source col + swizzled ds_read addr).
__global__ __launch_bounds__(256, 3)
void k_attn(const __hip_bfloat16* __restrict__ qb,
            const __hip_bfloat16* __restrict__ kb,
            const __hip_bfloat16* __restrict__ vtb,
            const float* __restrict__ x,
            float* __restrict__ y) {
  __shared__ alignas(16) __hip_bfloat16 Kl[64 * 128];   // [kv][c] swizzled
  __shared__ alignas(16) __hip_bfloat16 Vl[128 * 64];   // [c][kv] swizzled
  __shared__ alignas(16) __hip_bfloat16 Pl[4 * 16 * 72];
  int tid = threadIdx.x, w = tid >> 6, lane = tid & 63;
  int lr = lane >> 4, lc = lane & 15;
  int sxz = (lc & 7) << 3;                 // read-side XOR (elems)
  int qt = blockIdx.x, bh = blockIdx.y;
  int b_ = bh >> 3, h = bh & 7;
  int q0 = qt * 64;
  size_t bhN = (size_t)bh * 2048;

  // Q fragment: wave owns q rows [q0 + w*16, +16); A-frag row = lc
  bf16x8 qf[4];
#pragma unroll
  for (int ks = 0; ks < 4; ks++)
    qf[ks] = *(const bf16x8*)(qb + (bhN + q0 + w * 16 + lc) * 128 + ks * 32 + lr * 8);

  f32x4 oacc[8] = {};
  float mrun[4], lrun[4];
#pragma unroll
  for (int r = 0; r < 4; r++) { mrun[r] = -1e30f; lrun[r] = 0.f; }

  // staging: linear LDS dest, source column pre-swizzled by row&7
  int krow = tid >> 4;                                   // kv row 0..15 (+p*16)
  int kcol = ((tid & 15) * 8) ^ ((krow & 7) << 3);       // elems within 128
  const __hip_bfloat16* kG = kb + (bhN + krow) * 128 + kcol;
  int vrow = tid >> 3;                                   // c row 0..31 (+p*32)
  int vcol = ((tid & 7) * 8) ^ ((vrow & 7) << 3);        // elems within 64
  const __hip_bfloat16* vG = vtb + ((size_t)bh * 128 + vrow) * 2048 + vcol;
  char* kB = (char*)Kl + w * 1024;
  char* vB = (char*)Vl + w * 1024;

  for (int kv0 = 0; kv0 < 2048; kv0 += 64) {
#pragma unroll
    for (int p = 0; p < 4; p++)
      gload16(kG + (size_t)(kv0 + p * 16) * 128, kB + p * 4096);
#pragma unroll
    for (int p = 0; p < 4; p++)
      gload16(vG + kv0 + (size_t)p * 32 * 2048, vB + p * 4096);
    __syncthreads();

    // S = Q K^T : 16 q rows x 64 kv cols per wave
    f32x4 sf[4] = {};
#pragma unroll
    for (int ks = 0; ks < 4; ks++) {
      bf16x8 kfr[4];
#pragma unroll
      for (int ni = 0; ni < 4; ni++)
        kfr[ni] = *(const bf16x8*)(Kl + (ni * 16 + lc) * 128 + ((ks * 32 + lr * 8) ^ sxz));
#pragma unroll
      for (int ni = 0; ni < 4; ni++)
        sf[ni] = __builtin_amdgcn_mfma_f32_16x16x32_bf16(qf[ks], kfr[ni], sf[ni], 0, 0, 0);
    }

    // online softmax (rows lr*4+r, reduce across 16-lane groups)
#pragma unroll
    for (int r = 0; r < 4; r++) {
      float tmax = fmaxf(fmaxf(sf[0][r], sf[1][r]), fmaxf(sf[2][r], sf[3][r]));
#pragma unroll
      for (int off = 1; off < 16; off <<= 1) tmax = fmaxf(tmax, __shfl_xor(tmax, off, 16));
      tmax *= ATT_SCALE;
      float mnew = fmaxf(mrun[r], tmax);
      float alpha = __expf(mrun[r] - mnew);
      mrun[r] = mnew;
      float rs = 0.f;
#pragma unroll
      for (int ni = 0; ni < 4; ni++) {
        float p = __expf(sf[ni][r] * ATT_SCALE - mnew);
        sf[ni][r] = p;
        rs += p;
      }
#pragma unroll
      for (int off = 1; off < 16; off <<= 1) rs += __shfl_xor(rs, off, 16);
      lrun[r] = lrun[r] * alpha + rs;
#pragma unroll
      for (int nc = 0; nc < 8; nc++) oacc[nc][r] *= alpha;
    }

    // P -> LDS (per-wave region, 72-elem padded rows: conflict-free)
#pragma unroll
    for (int ni = 0; ni < 4; ni++)
#pragma unroll
      for (int r = 0; r < 4; r++)
        Pl[w * 1152 + (lr * 4 + r) * 72 + ni * 16 + lc] = __float2bfloat16(sf[ni][r]);
    asm volatile("s_waitcnt lgkmcnt(0)" ::: "memory");

    // O += P V
#pragma unroll
    for (int ks2 = 0; ks2 < 2; ks2++) {
      bf16x8 pa = *(const bf16x8*)(Pl + w * 1152 + lc * 72 + ks2 * 32 + lr * 8);
#pragma unroll
      for (int nc = 0; nc < 8; nc++) {
        bf16x8 vf = *(const bf16x8*)(Vl + (nc * 16 + lc) * 64 + ((ks2 * 32 + lr * 8) ^ sxz));
        oacc[nc] = __builtin_amdgcn_mfma_f32_16x16x32_bf16(pa, vf, oacc[nc], 0, 0, 0);
      }
    }
    __syncthreads();
  }

  // epilogue: y = O/l + x
#pragma unroll
  for (int r = 0; r < 4; r++) {
    int n = q0 + w * 16 + lr * 4 + r;
    float inv = 1.f / lrun[r];
    size_t base = ((size_t)(b_ * 2048 + n)) * 1024 + h * 128;
#pragma unroll
    for (int nc = 0; nc < 8; nc++) {
      int c = nc * 16 + lc;
      y[base + c] = oacc[nc][r] * inv + x[base + c];
    }
  }
}

// ---------------- launch ----------------
extern "C" void kernel_launch(void* const* d_in, const int* in_sizes, int n_in,
                              void* d_out, int out_size, void* d_ws, size_t ws_size,
                              hipStream_t stream) {
  const float* x   = (const float*)d_in[0];
  const float* lng = (const float*)d_in[1];
  const float* lnb = (const float*)d_in[2];
  const float* w3  = (const float*)d_in[3];
  const float* b3  = (const float*)d_in[4];
  const float* w1  = (const float*)d_in[5];
  const float* b1  = (const float*)d_in[6];
  const float* w2  = (const float*)d_in[7];
  const float* b2  = (const float*)d_in[8];
  float* out = (float*)d_out;

  constexpr size_t M = 8192;
  __hip_bfloat16* w3t  = (__hip_bfloat16*)d_ws;                 // [3072][1024]
  __hip_bfloat16* w1t  = w3t + (size_t)3072 * 1024;             // [4096][1024]
  __hip_bfloat16* w2t  = w1t + (size_t)4096 * 1024;             // [1024][4096]
  __hip_bfloat16* xln  = w2t + (size_t)4096 * 1024;             // [8192][1024] (also y1)
  __hip_bfloat16* qb   = xln + M * 1024;                        // [32][2048][128]
  __hip_bfloat16* kbuf = qb + M * 1024;
  __hip_bfloat16* vtb  = kbuf + M * 1024;
  __hip_bfloat16* hmid = qb;                                    // overlay: [8192][4096]

  k_transpose<1><<<dim3(48, 16), 256, 0, stream>>>(w3, w3t, 1024, 3072);
  k_transpose<0><<<dim3(64, 16), 256, 0, stream>>>(w1, w1t, 1024, 4096);
  k_transpose<0><<<dim3(16, 64), 256, 0, stream>>>(w2, w2t, 4096, 1024);
  k_ln<<<dim3(M), 256, 0, stream>>>(x, lng, lnb, xln);
  k_gemm<0><<<dim3(24, 64), 256, 0, stream>>>(xln, w3t, b3, nullptr, nullptr,
                                              qb, kbuf, vtb, 1024, 3072);
  k_attn<<<dim3(32, 32), 256, 0, stream>>>(qb, kbuf, vtb, x, out);
  k_ln<<<dim3(M), 256, 0, stream>>>(out, lng, lnb, xln);
  k_gemm<1><<<dim3(32, 64), 256, 0, stream>>>(xln, w1t, b1, nullptr, nullptr,
                                              hmid, nullptr, nullptr, 1024, 4096);
  k_gemm<2><<<dim3(8, 64), 256, 0, stream>>>(hmid, w2t, b2, out, out,
                                             nullptr, nullptr, nullptr, 4096, 1024);
}